// Round 6
// baseline (158.522 us; speedup 1.0000x reference)
//
#include <hip/hip_runtime.h>

// MHSA: B=2, T=2048, C=1024, H=16, hd=64. Inputs f32, output f32.
// cvt(x,Wqkv,Wproj->bf16, one launch) -> QKV GEMM (XCD-swizzled; scatter
// Q*0.125*log2e, K, V^T) -> flash attn (swapped QK^T, 32q/wave, defer-max,
// exp2 domain, transposed PV) -> proj GEMM (XCD-swizzled, f32 out).

typedef __bf16 bf16x4 __attribute__((ext_vector_type(4)));
typedef __bf16 bf16x8 __attribute__((ext_vector_type(8)));
typedef float  f32x4  __attribute__((ext_vector_type(4)));

#define AS1(p) ((const __attribute__((address_space(1))) void*)(p))
#define AS3(p) ((__attribute__((address_space(3))) void*)(p))

// ---------------------------------------------------------------------------
// One-shot f32->bf16 convert of the three tensors (grid-stride, float4).
// ---------------------------------------------------------------------------
__global__ __launch_bounds__(256)
void cvt_all(const float* __restrict__ a, const float* __restrict__ b,
             const float* __restrict__ c, __bf16* __restrict__ oa,
             __bf16* __restrict__ ob, __bf16* __restrict__ oc,
             int na, int nb, int nc)
{
    const int total = (na + nb + nc) >> 2;
    const int stride = gridDim.x * blockDim.x;
    for (int i4 = blockIdx.x * blockDim.x + threadIdx.x; i4 < total; i4 += stride) {
        int i = i4 << 2;
        const float* src; __bf16* dst;
        if (i < na)               { src = a + i;            dst = oa + i; }
        else if (i < na + nb)     { src = b + (i - na);     dst = ob + (i - na); }
        else                      { src = c + (i - na - nb); dst = oc + (i - na - nb); }
        const float4 v = *(const float4*)src;
        bf16x4 o = { (__bf16)v.x, (__bf16)v.y, (__bf16)v.z, (__bf16)v.w };
        *(bf16x4*)dst = o;
    }
}

// ---------------------------------------------------------------------------
// GEMM out[m][n] = sum_k A[m][k]*W[n][k] + bias[n]. 128x128 tile, BK=64.
// XCD-bijective block swizzle (grid % 8 == 0 for both call sites).
// MODE 0: QKV scatter epilogue (bf16, Q scaled to exp2 domain).
// MODE 1: f32 out (final projection).
// ---------------------------------------------------------------------------
template<int MODE>
__global__ __launch_bounds__(256)
void gemm_bt(const __bf16* __restrict__ A, const __bf16* __restrict__ W,
             const float* __restrict__ bias, int M, int N, int K,
             __bf16* __restrict__ O0, __bf16* __restrict__ O1,
             __bf16* __restrict__ O2, float* __restrict__ Of)
{
    __shared__ __bf16 sA[128 * 64];
    __shared__ __bf16 sB[128 * 64];
    const int tid  = threadIdx.x;
    const int w    = tid >> 6, lane = tid & 63;
    const int g    = lane >> 4, r16 = lane & 15;
    // XCD swizzle: consecutive new-ids land on one XCD (round-robin HW map).
    const int lin  = blockIdx.y * gridDim.x + blockIdx.x;
    const int per  = (gridDim.x * gridDim.y) >> 3;
    const int nlin = (lin & 7) * per + (lin >> 3);
    const int tM   = (nlin / gridDim.x) * 128, tN = (nlin % gridDim.x) * 128;
    const int wr   = w >> 1, wc = w & 1;
    const int crow = lane >> 3;
    const int ccol = (lane & 7) * 8;

    f32x4 acc[4][4] = {};

    for (int k0 = 0; k0 < K; k0 += 64) {
#pragma unroll
        for (int c = w; c < 16; c += 4) {
            const __bf16* ga = A + (size_t)(tM + c * 8 + crow) * K + k0 + ccol;
            __builtin_amdgcn_global_load_lds(AS1(ga), AS3(&sA[c * 8 * 64]), 16, 0, 0);
            const __bf16* gb = W + (size_t)(tN + c * 8 + crow) * K + k0 + ccol;
            __builtin_amdgcn_global_load_lds(AS1(gb), AS3(&sB[c * 8 * 64]), 16, 0, 0);
        }
        __syncthreads();
#pragma unroll
        for (int kk = 0; kk < 2; ++kk) {
            bf16x8 a[4], b[4];
#pragma unroll
            for (int mf = 0; mf < 4; ++mf)
                a[mf] = *(const bf16x8*)&sA[(wr * 64 + mf * 16 + r16) * 64 + kk * 32 + g * 8];
#pragma unroll
            for (int nf = 0; nf < 4; ++nf)
                b[nf] = *(const bf16x8*)&sB[(wc * 64 + nf * 16 + r16) * 64 + kk * 32 + g * 8];
#pragma unroll
            for (int mf = 0; mf < 4; ++mf)
#pragma unroll
                for (int nf = 0; nf < 4; ++nf)
                    acc[mf][nf] = __builtin_amdgcn_mfma_f32_16x16x32_bf16(
                        a[mf], b[nf], acc[mf][nf], 0, 0, 0);
        }
        __syncthreads();
    }

#pragma unroll
    for (int mf = 0; mf < 4; ++mf) {
#pragma unroll
        for (int nf = 0; nf < 4; ++nf) {
#pragma unroll
            for (int reg = 0; reg < 4; ++reg) {
                const int row = tM + wr * 64 + mf * 16 + g * 4 + reg;
                const int col = tN + wc * 64 + nf * 16 + r16;
                float v = acc[mf][nf][reg] + bias[col];
                if (MODE == 0) {
                    const int h = col / 192, j = col % 192;
                    const int b = row >> 11, t = row & 2047;
                    const size_t bh = (size_t)(b * 16 + h);
                    if (j < 64)   // Q: scale 0.125 * log2(e) -> exp2-domain softmax
                        O0[(bh * 2048 + t) * 64 + j] = (__bf16)(v * 0.18033688011112042f);
                    else if (j < 128)
                        O1[(bh * 2048 + t) * 64 + (j - 64)] = (__bf16)v;
                    else
                        O2[(bh * 64 + (j - 128)) * 2048 + t] = (__bf16)v;
                } else {
                    Of[(size_t)row * N + col] = v;
                }
            }
        }
    }
}

// ---------------------------------------------------------------------------
// Flash attention, swapped QK^T, 32 q/wave. Grid (32 qblocks, 16 heads, 2 b),
// 128 thr (2 waves, 64 q per block). K/V^T tiles (64 kv) staged in LDS (dbuf,
// XOR-swizzled); 8 LDS-read fragments feed 32 MFMAs per tile per wave.
// Softmax lane-local in exp2 domain with defer-max (THR=8). P_T through
// per-wave XOR-swizzled LDS. O_T = mfma(V_T, P_T) keeps rescale per-lane.
// ---------------------------------------------------------------------------
__global__ __launch_bounds__(128, 2)
void attn(const __bf16* __restrict__ Q, const __bf16* __restrict__ K,
          const __bf16* __restrict__ V, __bf16* __restrict__ O)
{
    __shared__ __bf16 sK[2][64 * 64];   // 8 KB each
    __shared__ __bf16 sV[2][64 * 64];   // V^T tile [d][kv]
    __shared__ __bf16 sP[64 * 64];      // [64 local q][64 kv], swizzled

    const int tid = threadIdx.x;
    const int w   = tid >> 6, lane = tid & 63;
    const int g   = lane >> 4, r16 = lane & 15;
    const int bh  = blockIdx.z * 16 + blockIdx.y;
    const int qw  = blockIdx.x * 64 + w * 32;          // wave's first q-row
    const __bf16* Qp = Q + (size_t)bh * 2048 * 64;
    const __bf16* Kp = K + (size_t)bh * 2048 * 64;
    const __bf16* Vp = V + (size_t)bh * 64 * 2048;

    const int srow = lane >> 3;                        // 0..7 within chunk
    const int scol = 8 * ((lane & 7) ^ srow);          // pre-swizzled src col
    const int swz  = (r16 & 7) << 4;                   // byte XOR for LDS reads

    // Q fragments (B-operand): lane r16 = q, k = d; h = q sub-block (0/1)
    bf16x8 qa[2][2];
#pragma unroll
    for (int h = 0; h < 2; ++h)
#pragma unroll
        for (int kk = 0; kk < 2; ++kk)
            qa[h][kk] = *(const bf16x8*)(Qp + (size_t)(qw + h * 16 + r16) * 64 + kk * 32 + g * 8);

    f32x4 o[2][4] = {};
    float mrun[2] = { -1e30f, -1e30f }, lrun[2] = { 0.f, 0.f };

    // ---- stage tile 0 (each wave stages 32 rows of K and of V^T) ----
#pragma unroll
    for (int r = 0; r < 4; ++r) {
        const int rb  = w * 32 + r * 8;
        const int row = rb + srow;
        __builtin_amdgcn_global_load_lds(AS1(Kp + (size_t)row * 64 + scol),
                                         AS3(&sK[0][rb * 64]), 16, 0, 0);
        __builtin_amdgcn_global_load_lds(AS1(Vp + (size_t)row * 2048 + scol),
                                         AS3(&sV[0][rb * 64]), 16, 0, 0);
    }
    __syncthreads();

    for (int t = 0; t < 32; ++t) {
        const int cur = t & 1;
        if (t < 31) {
            const int kvn = (t + 1) * 64;
#pragma unroll
            for (int r = 0; r < 4; ++r) {
                const int rb  = w * 32 + r * 8;
                const int row = rb + srow;
                __builtin_amdgcn_global_load_lds(AS1(Kp + (size_t)(kvn + row) * 64 + scol),
                                                 AS3(&sK[cur ^ 1][rb * 64]), 16, 0, 0);
                __builtin_amdgcn_global_load_lds(AS1(Vp + (size_t)row * 2048 + kvn + scol),
                                                 AS3(&sV[cur ^ 1][rb * 64]), 16, 0, 0);
            }
        }
        // ---- S_T[kv][q] = K Q^T ----
        bf16x8 kb[4][2];
#pragma unroll
        for (int nf = 0; nf < 4; ++nf) {
            const int row = nf * 16 + r16;
#pragma unroll
            for (int kk = 0; kk < 2; ++kk)
                kb[nf][kk] = *(const bf16x8*)((const char*)&sK[cur][0] + row * 128
                                              + ((kk * 64 + g * 16) ^ swz));
        }
        f32x4 S[2][4];
        __builtin_amdgcn_s_setprio(1);
#pragma unroll
        for (int h = 0; h < 2; ++h)
#pragma unroll
            for (int nf = 0; nf < 4; ++nf) {
                f32x4 s = {};
                s = __builtin_amdgcn_mfma_f32_16x16x32_bf16(kb[nf][0], qa[h][0], s, 0, 0, 0);
                s = __builtin_amdgcn_mfma_f32_16x16x32_bf16(kb[nf][1], qa[h][1], s, 0, 0, 0);
                S[h][nf] = s;
            }
        __builtin_amdgcn_s_setprio(0);
        // ---- softmax (exp2 domain), defer-max THR=8 ----
        float rm[2];
#pragma unroll
        for (int h = 0; h < 2; ++h) {
            float m0 = fmaxf(fmaxf(S[h][0][0], S[h][0][1]), fmaxf(S[h][0][2], S[h][0][3]));
#pragma unroll
            for (int nf = 1; nf < 4; ++nf)
                m0 = fmaxf(m0, fmaxf(fmaxf(S[h][nf][0], S[h][nf][1]),
                                     fmaxf(S[h][nf][2], S[h][nf][3])));
            m0 = fmaxf(m0, __shfl_xor(m0, 16));
            m0 = fmaxf(m0, __shfl_xor(m0, 32));
            rm[h] = m0;
        }
        if (!__all(rm[0] <= mrun[0] + 8.f && rm[1] <= mrun[1] + 8.f)) {
#pragma unroll
            for (int h = 0; h < 2; ++h) {
                const float mn = fmaxf(mrun[h], rm[h]);
                const float al = exp2f(mrun[h] - mn);
#pragma unroll
                for (int df = 0; df < 4; ++df)
#pragma unroll
                    for (int reg = 0; reg < 4; ++reg) o[h][df][reg] *= al;
                lrun[h] *= al;
                mrun[h] = mn;
            }
        }
#pragma unroll
        for (int h = 0; h < 2; ++h) {
            float ps = 0.f;
#pragma unroll
            for (int nf = 0; nf < 4; ++nf)
#pragma unroll
                for (int reg = 0; reg < 4; ++reg) {
                    const float p = exp2f(S[h][nf][reg] - mrun[h]);
                    S[h][nf][reg] = p;
                    ps += p;
                }
            lrun[h] += ps;
        }
        // ---- P_T -> per-wave LDS rows (packed 8B writes, XOR-swizzled) ----
        asm volatile("s_waitcnt lgkmcnt(0)" ::: "memory");   // WAR vs prev reads
        __builtin_amdgcn_sched_barrier(0);
#pragma unroll
        for (int h = 0; h < 2; ++h) {
            char* const Pb = (char*)sP + (w * 32 + h * 16 + r16) * 128;
#pragma unroll
            for (int nf = 0; nf < 4; ++nf) {
                bf16x4 pk = { (__bf16)S[h][nf][0], (__bf16)S[h][nf][1],
                              (__bf16)S[h][nf][2], (__bf16)S[h][nf][3] };
                *(bf16x4*)(Pb + ((nf * 32 + g * 8) ^ swz)) = pk;
            }
        }
        asm volatile("s_waitcnt lgkmcnt(0)" ::: "memory");   // writes visible
        __builtin_amdgcn_sched_barrier(0);
        // ---- O_T += V_T P_T ----
        bf16x8 pb[2][2];
#pragma unroll
        for (int h = 0; h < 2; ++h) {
            const char* Pb = (const char*)sP + (w * 32 + h * 16 + r16) * 128;
#pragma unroll
            for (int kk = 0; kk < 2; ++kk)
                pb[h][kk] = *(const bf16x8*)(Pb + ((kk * 64 + g * 16) ^ swz));
        }
        __builtin_amdgcn_s_setprio(1);
#pragma unroll
        for (int kk = 0; kk < 2; ++kk)
#pragma unroll
            for (int df = 0; df < 4; ++df) {
                const int row = df * 16 + r16;
                bf16x8 vb = *(const bf16x8*)((const char*)&sV[cur][0] + row * 128
                                             + ((kk * 64 + g * 16) ^ swz));
#pragma unroll
                for (int h = 0; h < 2; ++h)
                    o[h][df] = __builtin_amdgcn_mfma_f32_16x16x32_bf16(vb, pb[h][kk], o[h][df], 0, 0, 0);
            }
        __builtin_amdgcn_s_setprio(0);
        __syncthreads();   // waves done with cur + stage of next complete
    }

    // ---- finish denominators and store O_T -> Os[token][c] ----
#pragma unroll
    for (int h = 0; h < 2; ++h) {
        float l = lrun[h];
        l += __shfl_xor(l, 16);
        l += __shfl_xor(l, 32);
        const float inv = 1.f / l;
        const size_t token = (size_t)blockIdx.z * 2048 + qw + h * 16 + r16;
#pragma unroll
        for (int df = 0; df < 4; ++df) {
            bf16x4 ov = { (__bf16)(o[h][df][0] * inv), (__bf16)(o[h][df][1] * inv),
                          (__bf16)(o[h][df][2] * inv), (__bf16)(o[h][df][3] * inv) };
            *(bf16x4*)(O + token * 1024 + blockIdx.y * 64 + df * 16 + g * 4) = ov;
        }
    }
}

// ---------------------------------------------------------------------------
extern "C" void kernel_launch(void* const* d_in, const int* in_sizes, int n_in,
                              void* d_out, int out_size, void* d_ws, size_t ws_size,
                              hipStream_t stream)
{
    const float* x     = (const float*)d_in[0];
    const float* Wqkv  = (const float*)d_in[1];
    const float* bqkv  = (const float*)d_in[2];
    const float* Wproj = (const float*)d_in[3];
    const float* bproj = (const float*)d_in[4];
    float* out = (float*)d_out;

    const size_t NX   = (size_t)4096 * 1024;
    const size_t NWQ  = (size_t)3072 * 1024;
    const size_t NWP  = (size_t)1024 * 1024;

    __bf16* xb  = (__bf16*)d_ws;
    __bf16* Wqb = xb  + NX;
    __bf16* Wpb = Wqb + NWQ;
    __bf16* Qs  = Wpb + NWP;           // (B,H,T,64), scaled 0.125*log2e
    __bf16* Ks  = Qs  + NX;            // (B,H,T,64)
    __bf16* Vt  = Ks  + NX;            // (B,H,64,T)
    __bf16* Os  = Vt  + NX;            // (B*T, C)

    cvt_all<<<dim3(2048), dim3(256), 0, stream>>>(x, Wqkv, Wproj, xb, Wqb, Wpb,
                                                  (int)NX, (int)NWQ, (int)NWP);
    gemm_bt<0><<<dim3(24, 32), dim3(256), 0, stream>>>(xb, Wqb, bqkv, 4096, 3072, 1024, Qs, Ks, Vt, nullptr);
    attn<<<dim3(32, 16, 2), dim3(128), 0, stream>>>(Qs, Ks, Vt, Os);
    gemm_bt<1><<<dim3(8, 32), dim3(256), 0, stream>>>(Os, Wpb, bproj, 4096, 1024, 1024, nullptr, nullptr, nullptr, out);
}

// Round 7
// 148.567 us; speedup vs baseline: 1.0670x; 1.0670x over previous
//
#include <hip/hip_runtime.h>

// MHSA: B=2, T=2048, C=1024, H=16, hd=64. Inputs f32, output f32.
// cvt(all->bf16) -> QKV GEMM (XCD-swizzled; scatter Q*0.125*log2e, K, V^T)
// -> flash attn (swapped QK^T, 16q/wave, defer-max, exp2 domain, transposed
// PV, bh-grouped XCD remap) -> proj GEMM (XCD-swizzled, f32 out).

typedef __bf16 bf16x4 __attribute__((ext_vector_type(4)));
typedef __bf16 bf16x8 __attribute__((ext_vector_type(8)));
typedef float  f32x4  __attribute__((ext_vector_type(4)));

#define AS1(p) ((const __attribute__((address_space(1))) void*)(p))
#define AS3(p) ((__attribute__((address_space(3))) void*)(p))

// ---------------------------------------------------------------------------
__global__ __launch_bounds__(256)
void cvt_all(const float* __restrict__ a, const float* __restrict__ b,
             const float* __restrict__ c, __bf16* __restrict__ oa,
             __bf16* __restrict__ ob, __bf16* __restrict__ oc,
             int na, int nb, int nc)
{
    const int total = (na + nb + nc) >> 2;
    const int stride = gridDim.x * blockDim.x;
    for (int i4 = blockIdx.x * blockDim.x + threadIdx.x; i4 < total; i4 += stride) {
        int i = i4 << 2;
        const float* src; __bf16* dst;
        if (i < na)               { src = a + i;             dst = oa + i; }
        else if (i < na + nb)     { src = b + (i - na);      dst = ob + (i - na); }
        else                      { src = c + (i - na - nb); dst = oc + (i - na - nb); }
        const float4 v = *(const float4*)src;
        bf16x4 o = { (__bf16)v.x, (__bf16)v.y, (__bf16)v.z, (__bf16)v.w };
        *(bf16x4*)dst = o;
    }
}

// ---------------------------------------------------------------------------
// GEMM out[m][n] = sum_k A[m][k]*W[n][k] + bias[n]. 128x128 tile, BK=64.
// XCD-bijective block swizzle. MODE 0: QKV scatter epilogue. MODE 1: f32 out.
// ---------------------------------------------------------------------------
template<int MODE>
__global__ __launch_bounds__(256)
void gemm_bt(const __bf16* __restrict__ A, const __bf16* __restrict__ W,
             const float* __restrict__ bias, int M, int N, int K,
             __bf16* __restrict__ O0, __bf16* __restrict__ O1,
             __bf16* __restrict__ O2, float* __restrict__ Of)
{
    __shared__ __bf16 sA[128 * 64];
    __shared__ __bf16 sB[128 * 64];
    const int tid  = threadIdx.x;
    const int w    = tid >> 6, lane = tid & 63;
    const int g    = lane >> 4, r16 = lane & 15;
    const int lin  = blockIdx.y * gridDim.x + blockIdx.x;
    const int per  = (gridDim.x * gridDim.y) >> 3;
    const int nlin = (lin & 7) * per + (lin >> 3);
    const int tM   = (nlin / gridDim.x) * 128, tN = (nlin % gridDim.x) * 128;
    const int wr   = w >> 1, wc = w & 1;
    const int crow = lane >> 3;
    const int ccol = (lane & 7) * 8;

    f32x4 acc[4][4] = {};

    for (int k0 = 0; k0 < K; k0 += 64) {
#pragma unroll
        for (int c = w; c < 16; c += 4) {
            const __bf16* ga = A + (size_t)(tM + c * 8 + crow) * K + k0 + ccol;
            __builtin_amdgcn_global_load_lds(AS1(ga), AS3(&sA[c * 8 * 64]), 16, 0, 0);
            const __bf16* gb = W + (size_t)(tN + c * 8 + crow) * K + k0 + ccol;
            __builtin_amdgcn_global_load_lds(AS1(gb), AS3(&sB[c * 8 * 64]), 16, 0, 0);
        }
        __syncthreads();
#pragma unroll
        for (int kk = 0; kk < 2; ++kk) {
            bf16x8 a[4], b[4];
#pragma unroll
            for (int mf = 0; mf < 4; ++mf)
                a[mf] = *(const bf16x8*)&sA[(wr * 64 + mf * 16 + r16) * 64 + kk * 32 + g * 8];
#pragma unroll
            for (int nf = 0; nf < 4; ++nf)
                b[nf] = *(const bf16x8*)&sB[(wc * 64 + nf * 16 + r16) * 64 + kk * 32 + g * 8];
#pragma unroll
            for (int mf = 0; mf < 4; ++mf)
#pragma unroll
                for (int nf = 0; nf < 4; ++nf)
                    acc[mf][nf] = __builtin_amdgcn_mfma_f32_16x16x32_bf16(
                        a[mf], b[nf], acc[mf][nf], 0, 0, 0);
        }
        __syncthreads();
    }

#pragma unroll
    for (int mf = 0; mf < 4; ++mf) {
#pragma unroll
        for (int nf = 0; nf < 4; ++nf) {
#pragma unroll
            for (int reg = 0; reg < 4; ++reg) {
                const int row = tM + wr * 64 + mf * 16 + g * 4 + reg;
                const int col = tN + wc * 64 + nf * 16 + r16;
                float v = acc[mf][nf][reg] + bias[col];
                if (MODE == 0) {
                    const int h = col / 192, j = col % 192;
                    const int b = row >> 11, t = row & 2047;
                    const size_t bh = (size_t)(b * 16 + h);
                    if (j < 64)   // Q: 0.125 * log2(e) -> exp2-domain softmax
                        O0[(bh * 2048 + t) * 64 + j] = (__bf16)(v * 0.18033688011112042f);
                    else if (j < 128)
                        O1[(bh * 2048 + t) * 64 + (j - 64)] = (__bf16)v;
                    else
                        O2[(bh * 64 + (j - 128)) * 2048 + t] = (__bf16)v;
                } else {
                    Of[(size_t)row * N + col] = v;
                }
            }
        }
    }
}

// ---------------------------------------------------------------------------
// Flash attention, swapped QK^T, 16 q/wave, 4 waves/block. 1024 blocks.
// bh-grouped XCD remap: all 32 qblocks of a bh land on one XCD (K/V tiles
// L2-resident, ~2 MB/XCD). K/V^T staged in LDS (dbuf, XOR-swizzled).
// Softmax lane-local, exp2 domain, defer-max THR=8. P_T via per-wave LDS.
// ---------------------------------------------------------------------------
__global__ __launch_bounds__(256, 4)
void attn(const __bf16* __restrict__ Q, const __bf16* __restrict__ K,
          const __bf16* __restrict__ V, __bf16* __restrict__ O)
{
    __shared__ __bf16 sK[2][64 * 64];   // 8 KB each
    __shared__ __bf16 sV[2][64 * 64];   // V^T tile [d][kv]
    __shared__ __bf16 sP[64 * 64];      // 4 waves x [16 q][64 kv], swizzled

    const int tid = threadIdx.x;
    const int w   = tid >> 6, lane = tid & 63;
    const int g   = lane >> 4, r16 = lane & 15;
    // bijective remap of the 1024 linear ids: xcd gets 4 whole bh's
    const int m   = blockIdx.x + (blockIdx.y << 5) + (blockIdx.z << 9);
    const int bh  = (m & 7) + ((m >> 8) << 3);
    const int qb  = (m >> 3) & 31;
    const int q0  = qb * 64 + w * 16;
    const __bf16* Qp = Q + (size_t)bh * 2048 * 64;
    const __bf16* Kp = K + (size_t)bh * 2048 * 64;
    const __bf16* Vp = V + (size_t)bh * 64 * 2048;

    const int srow = lane >> 3;
    const int scol = 8 * ((lane & 7) ^ srow);   // pre-swizzled src col
    const int swz  = (r16 & 7) << 4;            // byte XOR for LDS reads
    char* const Pb = (char*)sP + (w * 16 + r16) * 128;

    // Q fragments (B-operand): lane r16 = q, k = d
    bf16x8 qa[2];
#pragma unroll
    for (int kk = 0; kk < 2; ++kk)
        qa[kk] = *(const bf16x8*)(Qp + (size_t)(q0 + r16) * 64 + kk * 32 + g * 8);

    f32x4 o[4] = {};
    float mrun = -1e30f, lrun = 0.f;

    // ---- stage tile 0 ----
#pragma unroll
    for (int r = 0; r < 2; ++r) {
        const int ldsb = r * 4096 + w * 1024;
        const int row  = r * 32 + w * 8 + srow;
        __builtin_amdgcn_global_load_lds(AS1(Kp + (size_t)row * 64 + scol),
                                         AS3((char*)&sK[0][0] + ldsb), 16, 0, 0);
        __builtin_amdgcn_global_load_lds(AS1(Vp + (size_t)row * 2048 + scol),
                                         AS3((char*)&sV[0][0] + ldsb), 16, 0, 0);
    }
    __syncthreads();

    for (int t = 0; t < 32; ++t) {
        const int cur = t & 1;
        if (t < 31) {
            const int kvn = (t + 1) * 64;
#pragma unroll
            for (int r = 0; r < 2; ++r) {
                const int ldsb = r * 4096 + w * 1024;
                const int row  = r * 32 + w * 8 + srow;
                __builtin_amdgcn_global_load_lds(AS1(Kp + (size_t)(kvn + row) * 64 + scol),
                                                 AS3((char*)&sK[cur ^ 1][0] + ldsb), 16, 0, 0);
                __builtin_amdgcn_global_load_lds(AS1(Vp + (size_t)row * 2048 + kvn + scol),
                                                 AS3((char*)&sV[cur ^ 1][0] + ldsb), 16, 0, 0);
            }
        }
        // ---- S_T[kv][q] = K Q^T ----
        bf16x8 kb[4][2];
#pragma unroll
        for (int nf = 0; nf < 4; ++nf) {
            const int row = nf * 16 + r16;
#pragma unroll
            for (int kk = 0; kk < 2; ++kk)
                kb[nf][kk] = *(const bf16x8*)((const char*)&sK[cur][0] + row * 128
                                              + ((kk * 64 + g * 16) ^ swz));
        }
        f32x4 S[4];
        __builtin_amdgcn_s_setprio(1);
#pragma unroll
        for (int nf = 0; nf < 4; ++nf) {
            f32x4 s = {};
            s = __builtin_amdgcn_mfma_f32_16x16x32_bf16(kb[nf][0], qa[0], s, 0, 0, 0);
            s = __builtin_amdgcn_mfma_f32_16x16x32_bf16(kb[nf][1], qa[1], s, 0, 0, 0);
            S[nf] = s;
        }
        __builtin_amdgcn_s_setprio(0);
        // ---- softmax (exp2 domain), lane-local + 2 shfls, defer-max ----
        float rm = fmaxf(fmaxf(S[0][0], S[0][1]), fmaxf(S[0][2], S[0][3]));
#pragma unroll
        for (int nf = 1; nf < 4; ++nf)
            rm = fmaxf(rm, fmaxf(fmaxf(S[nf][0], S[nf][1]), fmaxf(S[nf][2], S[nf][3])));
        rm = fmaxf(rm, __shfl_xor(rm, 16));
        rm = fmaxf(rm, __shfl_xor(rm, 32));
        if (!__all(rm <= mrun + 8.f)) {
            const float mn = fmaxf(mrun, rm);
            const float al = exp2f(mrun - mn);
#pragma unroll
            for (int df = 0; df < 4; ++df)
#pragma unroll
                for (int reg = 0; reg < 4; ++reg) o[df][reg] *= al;
            lrun *= al;
            mrun = mn;
        }
        float ps = 0.f;
#pragma unroll
        for (int nf = 0; nf < 4; ++nf)
#pragma unroll
            for (int reg = 0; reg < 4; ++reg) {
                const float p = exp2f(S[nf][reg] - mrun);
                S[nf][reg] = p;
                ps += p;
            }
        lrun += ps;
        // ---- P_T -> per-wave LDS (packed 8B writes, XOR-swizzled) ----
        asm volatile("s_waitcnt lgkmcnt(0)" ::: "memory");
        __builtin_amdgcn_sched_barrier(0);
#pragma unroll
        for (int nf = 0; nf < 4; ++nf) {
            bf16x4 pk = { (__bf16)S[nf][0], (__bf16)S[nf][1],
                          (__bf16)S[nf][2], (__bf16)S[nf][3] };
            *(bf16x4*)(Pb + ((nf * 32 + g * 8) ^ swz)) = pk;
        }
        asm volatile("s_waitcnt lgkmcnt(0)" ::: "memory");
        __builtin_amdgcn_sched_barrier(0);
        // ---- O_T += V_T P_T ----
        bf16x8 pb[2];
#pragma unroll
        for (int kk = 0; kk < 2; ++kk)
            pb[kk] = *(const bf16x8*)(Pb + ((kk * 64 + g * 16) ^ swz));
        __builtin_amdgcn_s_setprio(1);
#pragma unroll
        for (int kk = 0; kk < 2; ++kk)
#pragma unroll
            for (int df = 0; df < 4; ++df) {
                const int row = df * 16 + r16;
                bf16x8 vb = *(const bf16x8*)((const char*)&sV[cur][0] + row * 128
                                             + ((kk * 64 + g * 16) ^ swz));
                o[df] = __builtin_amdgcn_mfma_f32_16x16x32_bf16(vb, pb[kk], o[df], 0, 0, 0);
            }
        __builtin_amdgcn_s_setprio(0);
        __syncthreads();
    }

    // ---- finish denominator and store O_T -> Os[token][c] ----
    lrun += __shfl_xor(lrun, 16);
    lrun += __shfl_xor(lrun, 32);
    const float inv = 1.f / lrun;
    const size_t token = (size_t)(bh >> 4) * 2048 + q0 + r16;
#pragma unroll
    for (int df = 0; df < 4; ++df) {
        bf16x4 ov = { (__bf16)(o[df][0] * inv), (__bf16)(o[df][1] * inv),
                      (__bf16)(o[df][2] * inv), (__bf16)(o[df][3] * inv) };
        *(bf16x4*)(O + token * 1024 + (bh & 15) * 64 + df * 16 + g * 4) = ov;
    }
}

// ---------------------------------------------------------------------------
extern "C" void kernel_launch(void* const* d_in, const int* in_sizes, int n_in,
                              void* d_out, int out_size, void* d_ws, size_t ws_size,
                              hipStream_t stream)
{
    const float* x     = (const float*)d_in[0];
    const float* Wqkv  = (const float*)d_in[1];
    const float* bqkv  = (const float*)d_in[2];
    const float* Wproj = (const float*)d_in[3];
    const float* bproj = (const float*)d_in[4];
    float* out = (float*)d_out;

    const size_t NX   = (size_t)4096 * 1024;
    const size_t NWQ  = (size_t)3072 * 1024;
    const size_t NWP  = (size_t)1024 * 1024;

    __bf16* xb  = (__bf16*)d_ws;
    __bf16* Wqb = xb  + NX;
    __bf16* Wpb = Wqb + NWQ;
    __bf16* Qs  = Wpb + NWP;           // (B,H,T,64), scaled 0.125*log2e
    __bf16* Ks  = Qs  + NX;            // (B,H,T,64)
    __bf16* Vt  = Ks  + NX;            // (B,H,64,T)
    __bf16* Os  = Vt  + NX;            // (B*T, C)

    cvt_all<<<dim3(2048), dim3(256), 0, stream>>>(x, Wqkv, Wproj, xb, Wqb, Wpb,
                                                  (int)NX, (int)NWQ, (int)NWP);
    gemm_bt<0><<<dim3(24, 32), dim3(256), 0, stream>>>(xb, Wqb, bqkv, 4096, 3072, 1024, Qs, Ks, Vt, nullptr);
    attn<<<dim3(32, 16, 2), dim3(256), 0, stream>>>(Qs, Ks, Vt, Os);
    gemm_bt<1><<<dim3(8, 32), dim3(256), 0, stream>>>(Os, Wpb, bproj, 4096, 1024, 1024, nullptr, nullptr, nullptr, out);
}

// Round 8
// 144.026 us; speedup vs baseline: 1.1006x; 1.0315x over previous
//
#include <hip/hip_runtime.h>

// MHSA: B=2, T=2048, C=1024, H=16, hd=64. Inputs f32, output f32.
// cvt(all->bf16) -> QKV GEMM (XCD-swizzled; scatter Q*0.125*log2e, K, V^T)
// -> flash attn (swapped QK^T; sigma-permuted K rows => P stays in registers;
// defer-max; exp2 domain; bh-grouped XCD remap) -> proj GEMM (f32 out).

typedef __bf16 bf16x4 __attribute__((ext_vector_type(4)));
typedef __bf16 bf16x8 __attribute__((ext_vector_type(8)));
typedef float  f32x4  __attribute__((ext_vector_type(4)));

#define AS1(p) ((const __attribute__((address_space(1))) void*)(p))
#define AS3(p) ((__attribute__((address_space(3))) void*)(p))

// ---------------------------------------------------------------------------
__global__ __launch_bounds__(256)
void cvt_all(const float* __restrict__ a, const float* __restrict__ b,
             const float* __restrict__ c, __bf16* __restrict__ oa,
             __bf16* __restrict__ ob, __bf16* __restrict__ oc,
             int na, int nb, int nc)
{
    const int total = (na + nb + nc) >> 2;
    const int stride = gridDim.x * blockDim.x;
    for (int i4 = blockIdx.x * blockDim.x + threadIdx.x; i4 < total; i4 += stride) {
        int i = i4 << 2;
        const float* src; __bf16* dst;
        if (i < na)               { src = a + i;             dst = oa + i; }
        else if (i < na + nb)     { src = b + (i - na);      dst = ob + (i - na); }
        else                      { src = c + (i - na - nb); dst = oc + (i - na - nb); }
        const float4 v = *(const float4*)src;
        bf16x4 o = { (__bf16)v.x, (__bf16)v.y, (__bf16)v.z, (__bf16)v.w };
        *(bf16x4*)dst = o;
    }
}

// ---------------------------------------------------------------------------
// GEMM out[m][n] = sum_k A[m][k]*W[n][k] + bias[n]. 128x128 tile, BK=64.
// XCD-bijective block swizzle. MODE 0: QKV scatter epilogue. MODE 1: f32 out.
// ---------------------------------------------------------------------------
template<int MODE>
__global__ __launch_bounds__(256)
void gemm_bt(const __bf16* __restrict__ A, const __bf16* __restrict__ W,
             const float* __restrict__ bias, int M, int N, int K,
             __bf16* __restrict__ O0, __bf16* __restrict__ O1,
             __bf16* __restrict__ O2, float* __restrict__ Of)
{
    __shared__ __bf16 sA[128 * 64];
    __shared__ __bf16 sB[128 * 64];
    const int tid  = threadIdx.x;
    const int w    = tid >> 6, lane = tid & 63;
    const int g    = lane >> 4, r16 = lane & 15;
    const int lin  = blockIdx.y * gridDim.x + blockIdx.x;
    const int per  = (gridDim.x * gridDim.y) >> 3;
    const int nlin = (lin & 7) * per + (lin >> 3);
    const int tM   = (nlin / gridDim.x) * 128, tN = (nlin % gridDim.x) * 128;
    const int wr   = w >> 1, wc = w & 1;
    const int crow = lane >> 3;
    const int ccol = (lane & 7) * 8;

    f32x4 acc[4][4] = {};

    for (int k0 = 0; k0 < K; k0 += 64) {
#pragma unroll
        for (int c = w; c < 16; c += 4) {
            const __bf16* ga = A + (size_t)(tM + c * 8 + crow) * K + k0 + ccol;
            __builtin_amdgcn_global_load_lds(AS1(ga), AS3(&sA[c * 8 * 64]), 16, 0, 0);
            const __bf16* gb = W + (size_t)(tN + c * 8 + crow) * K + k0 + ccol;
            __builtin_amdgcn_global_load_lds(AS1(gb), AS3(&sB[c * 8 * 64]), 16, 0, 0);
        }
        __syncthreads();
#pragma unroll
        for (int kk = 0; kk < 2; ++kk) {
            bf16x8 a[4], b[4];
#pragma unroll
            for (int mf = 0; mf < 4; ++mf)
                a[mf] = *(const bf16x8*)&sA[(wr * 64 + mf * 16 + r16) * 64 + kk * 32 + g * 8];
#pragma unroll
            for (int nf = 0; nf < 4; ++nf)
                b[nf] = *(const bf16x8*)&sB[(wc * 64 + nf * 16 + r16) * 64 + kk * 32 + g * 8];
#pragma unroll
            for (int mf = 0; mf < 4; ++mf)
#pragma unroll
                for (int nf = 0; nf < 4; ++nf)
                    acc[mf][nf] = __builtin_amdgcn_mfma_f32_16x16x32_bf16(
                        a[mf], b[nf], acc[mf][nf], 0, 0, 0);
        }
        __syncthreads();
    }

#pragma unroll
    for (int mf = 0; mf < 4; ++mf) {
#pragma unroll
        for (int nf = 0; nf < 4; ++nf) {
#pragma unroll
            for (int reg = 0; reg < 4; ++reg) {
                const int row = tM + wr * 64 + mf * 16 + g * 4 + reg;
                const int col = tN + wc * 64 + nf * 16 + r16;
                float v = acc[mf][nf][reg] + bias[col];
                if (MODE == 0) {
                    const int h = col / 192, j = col % 192;
                    const int b = row >> 11, t = row & 2047;
                    const size_t bh = (size_t)(b * 16 + h);
                    if (j < 64)   // Q: 0.125 * log2(e) -> exp2-domain softmax
                        O0[(bh * 2048 + t) * 64 + j] = (__bf16)(v * 0.18033688011112042f);
                    else if (j < 128)
                        O1[(bh * 2048 + t) * 64 + (j - 64)] = (__bf16)v;
                    else
                        O2[(bh * 64 + (j - 128)) * 2048 + t] = (__bf16)v;
                } else {
                    Of[(size_t)row * N + col] = v;
                }
            }
        }
    }
}

// ---------------------------------------------------------------------------
// Flash attention, swapped QK^T, 16 q/wave, 4 waves/block, 1024 blocks,
// bh-grouped XCD remap. K/V^T staged in LDS (dbuf, swizzled).
// K A-fragment rows are sigma-permuted: sigma(nf,m) = (nf>>1)*32 + (m>>2)*8
// + (nf&1)*4 + (m&3). Then QK^T output slot (nf,reg) at lane (g,r16) holds
// exactly the P element PV's B-fragment needs at (kk=nf>>1, j=(nf&1)*4+reg)
// with V in NATURAL order -> P never leaves registers (no LDS round-trip).
// K swizzle slot s(row) = (row&3)|(((row>>3)&1)<<2); V swizzle s = row&7.
// ---------------------------------------------------------------------------
__global__ __launch_bounds__(256, 4)
void attn(const __bf16* __restrict__ Q, const __bf16* __restrict__ K,
          const __bf16* __restrict__ V, __bf16* __restrict__ O)
{
    __shared__ __bf16 sK[2][64 * 64];   // 8 KB each
    __shared__ __bf16 sV[2][64 * 64];   // V^T tile [d][kv]

    const int tid = threadIdx.x;
    const int w   = tid >> 6, lane = tid & 63;
    const int g   = lane >> 4, r16 = lane & 15;
    // bijective remap of the 1024 linear ids: each XCD gets 4 whole bh's
    const int m   = blockIdx.x + (blockIdx.y << 5) + (blockIdx.z << 9);
    const int bh  = (m & 7) + ((m >> 8) << 3);
    const int qb  = (m >> 3) & 31;
    const int q0  = qb * 64 + w * 16;
    const __bf16* Qp = Q + (size_t)bh * 2048 * 64;
    const __bf16* Kp = K + (size_t)bh * 2048 * 64;
    const __bf16* Vp = V + (size_t)bh * 64 * 2048;

    const int srow  = lane >> 3;
    // staging source pre-swizzle (elements); involution XOR per row
    const int scolV = 8 * ((lane & 7) ^ srow);                             // s = row&7
    const int scolK = 8 * ((lane & 7) ^ ((srow & 3) | ((w & 1) << 2)));    // s = (row&3)|((row>>3&1)<<2); row>>3&1 == w&1
    // read-side swizzles (bytes)
    const int swzK  = ((r16 & 3) | (((r16 >> 2) & 1) << 2)) << 4;
    const int swzV  = (r16 & 7) << 4;

    // Q fragments (B-operand): lane r16 = q, k = d
    bf16x8 qa[2];
#pragma unroll
    for (int kk = 0; kk < 2; ++kk)
        qa[kk] = *(const bf16x8*)(Qp + (size_t)(q0 + r16) * 64 + kk * 32 + g * 8);

    f32x4 o[4] = {};
    float mrun = -1e30f, lrun = 0.f;

    // ---- stage tile 0 ----
#pragma unroll
    for (int r = 0; r < 2; ++r) {
        const int ldsb = r * 4096 + w * 1024;
        const int row  = r * 32 + w * 8 + srow;
        __builtin_amdgcn_global_load_lds(AS1(Kp + (size_t)row * 64 + scolK),
                                         AS3((char*)&sK[0][0] + ldsb), 16, 0, 0);
        __builtin_amdgcn_global_load_lds(AS1(Vp + (size_t)row * 2048 + scolV),
                                         AS3((char*)&sV[0][0] + ldsb), 16, 0, 0);
    }
    __syncthreads();

    for (int t = 0; t < 32; ++t) {
        const int cur = t & 1;
        if (t < 31) {
            const int kvn = (t + 1) * 64;
#pragma unroll
            for (int r = 0; r < 2; ++r) {
                const int ldsb = r * 4096 + w * 1024;
                const int row  = r * 32 + w * 8 + srow;
                __builtin_amdgcn_global_load_lds(AS1(Kp + (size_t)(kvn + row) * 64 + scolK),
                                                 AS3((char*)&sK[cur ^ 1][0] + ldsb), 16, 0, 0);
                __builtin_amdgcn_global_load_lds(AS1(Vp + (size_t)row * 2048 + kvn + scolV),
                                                 AS3((char*)&sV[cur ^ 1][0] + ldsb), 16, 0, 0);
            }
        }
        // ---- S_T[kv][q] = K Q^T with sigma-permuted K rows ----
        bf16x8 kb[4][2];
#pragma unroll
        for (int nf = 0; nf < 4; ++nf) {
            const int row = ((nf >> 1) << 5) + ((r16 >> 2) << 3) + ((nf & 1) << 2) + (r16 & 3);
#pragma unroll
            for (int kk = 0; kk < 2; ++kk)
                kb[nf][kk] = *(const bf16x8*)((const char*)&sK[cur][0] + row * 128
                                              + ((kk * 64 + g * 16) ^ swzK));
        }
        f32x4 S[4];
        __builtin_amdgcn_s_setprio(1);
#pragma unroll
        for (int nf = 0; nf < 4; ++nf) {
            f32x4 s = {};
            s = __builtin_amdgcn_mfma_f32_16x16x32_bf16(kb[nf][0], qa[0], s, 0, 0, 0);
            s = __builtin_amdgcn_mfma_f32_16x16x32_bf16(kb[nf][1], qa[1], s, 0, 0, 0);
            S[nf] = s;
        }
        __builtin_amdgcn_s_setprio(0);
        // ---- softmax (exp2 domain), lane-local + 2 shfls, defer-max ----
        float rm = fmaxf(fmaxf(S[0][0], S[0][1]), fmaxf(S[0][2], S[0][3]));
#pragma unroll
        for (int nf = 1; nf < 4; ++nf)
            rm = fmaxf(rm, fmaxf(fmaxf(S[nf][0], S[nf][1]), fmaxf(S[nf][2], S[nf][3])));
        rm = fmaxf(rm, __shfl_xor(rm, 16));
        rm = fmaxf(rm, __shfl_xor(rm, 32));
        if (!__all(rm <= mrun + 8.f)) {
            const float mn = fmaxf(mrun, rm);
            const float al = exp2f(mrun - mn);
#pragma unroll
            for (int df = 0; df < 4; ++df)
#pragma unroll
                for (int reg = 0; reg < 4; ++reg) o[df][reg] *= al;
            lrun *= al;
            mrun = mn;
        }
        float ps = 0.f;
#pragma unroll
        for (int nf = 0; nf < 4; ++nf)
#pragma unroll
            for (int reg = 0; reg < 4; ++reg) {
                const float p = exp2f(S[nf][reg] - mrun);
                S[nf][reg] = p;
                ps += p;
            }
        lrun += ps;
        // ---- P already register-resident: pb[kk][j] = S[kk*2+(j>>2)][j&3] ----
        bf16x8 pb[2];
#pragma unroll
        for (int kk = 0; kk < 2; ++kk) {
            bf16x8 tpk;
            tpk[0] = (__bf16)S[kk * 2][0];     tpk[1] = (__bf16)S[kk * 2][1];
            tpk[2] = (__bf16)S[kk * 2][2];     tpk[3] = (__bf16)S[kk * 2][3];
            tpk[4] = (__bf16)S[kk * 2 + 1][0]; tpk[5] = (__bf16)S[kk * 2 + 1][1];
            tpk[6] = (__bf16)S[kk * 2 + 1][2]; tpk[7] = (__bf16)S[kk * 2 + 1][3];
            pb[kk] = tpk;
        }
        // ---- O_T += V_T P_T (V natural kv order) ----
        __builtin_amdgcn_s_setprio(1);
#pragma unroll
        for (int kk = 0; kk < 2; ++kk)
#pragma unroll
            for (int df = 0; df < 4; ++df) {
                const int row = df * 16 + r16;
                bf16x8 vb = *(const bf16x8*)((const char*)&sV[cur][0] + row * 128
                                             + ((kk * 64 + g * 16) ^ swzV));
                o[df] = __builtin_amdgcn_mfma_f32_16x16x32_bf16(vb, pb[kk], o[df], 0, 0, 0);
            }
        __builtin_amdgcn_s_setprio(0);
        __syncthreads();
    }

    // ---- finish denominator and store O_T -> Os[token][c] ----
    lrun += __shfl_xor(lrun, 16);
    lrun += __shfl_xor(lrun, 32);
    const float inv = 1.f / lrun;
    const size_t token = (size_t)(bh >> 4) * 2048 + q0 + r16;
#pragma unroll
    for (int df = 0; df < 4; ++df) {
        bf16x4 ov = { (__bf16)(o[df][0] * inv), (__bf16)(o[df][1] * inv),
                      (__bf16)(o[df][2] * inv), (__bf16)(o[df][3] * inv) };
        *(bf16x4*)(O + token * 1024 + (bh & 15) * 64 + df * 16 + g * 4) = ov;
    }
}

// ---------------------------------------------------------------------------
extern "C" void kernel_launch(void* const* d_in, const int* in_sizes, int n_in,
                              void* d_out, int out_size, void* d_ws, size_t ws_size,
                              hipStream_t stream)
{
    const float* x     = (const float*)d_in[0];
    const float* Wqkv  = (const float*)d_in[1];
    const float* bqkv  = (const float*)d_in[2];
    const float* Wproj = (const float*)d_in[3];
    const float* bproj = (const float*)d_in[4];
    float* out = (float*)d_out;

    const size_t NX   = (size_t)4096 * 1024;
    const size_t NWQ  = (size_t)3072 * 1024;
    const size_t NWP  = (size_t)1024 * 1024;

    __bf16* xb  = (__bf16*)d_ws;
    __bf16* Wqb = xb  + NX;
    __bf16* Wpb = Wqb + NWQ;
    __bf16* Qs  = Wpb + NWP;           // (B,H,T,64), scaled 0.125*log2e
    __bf16* Ks  = Qs  + NX;            // (B,H,T,64)
    __bf16* Vt  = Ks  + NX;            // (B,H,64,T)
    __bf16* Os  = Vt  + NX;            // (B*T, C)

    cvt_all<<<dim3(2048), dim3(256), 0, stream>>>(x, Wqkv, Wproj, xb, Wqb, Wpb,
                                                  (int)NX, (int)NWQ, (int)NWP);
    gemm_bt<0><<<dim3(24, 32), dim3(256), 0, stream>>>(xb, Wqb, bqkv, 4096, 3072, 1024, Qs, Ks, Vt, nullptr);
    attn<<<dim3(32, 16, 2), dim3(256), 0, stream>>>(Qs, Ks, Vt, Os);
    gemm_bt<1><<<dim3(8, 32), dim3(256), 0, stream>>>(Os, Wpb, bproj, 4096, 1024, 1024, nullptr, nullptr, nullptr, out);
}